// Round 2
// baseline (264.414 us; speedup 1.0000x reference)
//
#include <hip/hip_runtime.h>

#define IH 256
#define IW 256
#define FH 128
#define FW 128
#define NB 16
#define ICH 33
#define NF 10
#define NC 30            // warped channels = NF*3
#define PL (FH * FW)     // 16384
#define NPLANE (NB * ICH)                    // 528 resized planes
#define RS_FLOATS (NPLANE * PL)              // 8.65M floats = 34.6 MB in ws
#define RSZ_BLOCKS (NPLANE * 4)              // 2112: quarter-plane per block
#define SMOOTH_BLOCKS 480
#define LOSS_SPLIT 4                         // parts per (b,c) -- matches round-0 sum order
#define LOSS_BLOCKS (NB * NC * LOSS_SPLIT)   // 1920 (multiple of 8 for XCD swizzle)
#define PART_STRIDE 8

// fast exact charbonnier: (g^2 + 1e-6)^0.4, arg > 0 so hw log2/exp2 safe (~1ulp)
__device__ __forceinline__ float charb(float g) {
    float t = fmaf(g, g, 1e-6f);
    return __builtin_amdgcn_exp2f(0.4f * __builtin_amdgcn_logf(t));
}

// align-corners bilinear sample of a 256x256 plane at 128-grid point (Y,X).
// Bit-exact vs jax reference (absmax 0.0 across prior rounds).
__device__ __forceinline__ float resized_at(const float* __restrict__ plane, int Y, int X) {
    const float s = (float)(255.0 / 127.0);
    float fy = (float)Y * s;
    float fx = (float)X * s;
    int y0 = (int)fy; y0 = y0 > IH - 2 ? IH - 2 : y0;
    int x0 = (int)fx; x0 = x0 > IW - 2 ? IW - 2 : x0;
    float wy = fy - (float)y0;
    float wx = fx - (float)x0;
    const float* p0 = plane + y0 * IW + x0;
    float v00 = p0[0], v01 = p0[1];
    float v10 = p0[IW], v11 = p0[IW + 1];
    float r0 = v00 * (1.f - wy) + v10 * wy;   // y-interp first (matches reference)
    float r1 = v01 * (1.f - wy) + v11 * wy;
    return r0 * (1.f - wx) + r1 * wx;
}

// ============ Pass 1: materialize all resized planes + smoothness partials =========
// blocks [0, 2112): resize one quarter-plane each (streaming read of images,
// coalesced float2 write of 34.6 MB into ws -> L3-hot for pass 2).
// blocks [2112, 2592): smoothness partial sums (independent of resize).
__global__ void __launch_bounds__(256, 8) resize_smooth(const float* __restrict__ images,
                                                        const float* __restrict__ flows,
                                                        float* __restrict__ ws)
{
    if (blockIdx.x < RSZ_BLOCKS) {
        int plane = blockIdx.x >> 2;
        int quarter = blockIdx.x & 3;
        const float* img = images + (size_t)plane * (IH * IW);
        float2* outp = (float2*)ws + (size_t)plane * (PL / 2);
        #pragma unroll 4
        for (int k = 0; k < 8; k++) {
            int p2 = quarter * 2048 + (int)threadIdx.x + k * 256;
            int Y = p2 >> 6;
            int X = (p2 & 63) * 2;
            float r0 = resized_at(img, Y, X);
            float r1 = resized_at(img, Y, X + 1);
            outp[p2] = make_float2(r0, r1);
        }
        return;
    }

    // ---------- smoothness partial: gradient along flow-index axis and H axis ----
    float* part_smooth = ws + RS_FLOATS + LOSS_BLOCKS * PART_STRIDE;
    int sb = blockIdx.x - RSZ_BLOCKS;
    const int total = NB * NF * PL;
    float s = 0.f;
    for (int i = sb * 256 + threadIdx.x; i < total; i += SMOOTH_BLOCKS * 256) {
        int w = i & (FW - 1);
        int h = (i >> 7) & (FH - 1);
        int f = (i >> 14) % NF;
        int b = i / (NF * PL);
        int pix = h * FW + w;
        const float* xp = flows + (size_t)(b * 2 * NF + 2 * f) * PL;
        const float* yp = xp + PL;

        float g1x, g1y;   // flow-channel axis (stride 2 planes)
        if (f == 0)           { g1x = xp[2 * PL + pix] - xp[pix];
                                g1y = yp[2 * PL + pix] - yp[pix]; }
        else if (f == NF - 1) { g1x = xp[pix] - xp[pix - 2 * PL];
                                g1y = yp[pix] - yp[pix - 2 * PL]; }
        else                  { g1x = 0.5f * (xp[2 * PL + pix] - xp[pix - 2 * PL]);
                                g1y = 0.5f * (yp[2 * PL + pix] - yp[pix - 2 * PL]); }

        float g2x, g2y;   // H axis
        if (h == 0)           { g2x = xp[pix + FW] - xp[pix];
                                g2y = yp[pix + FW] - yp[pix]; }
        else if (h == FH - 1) { g2x = xp[pix] - xp[pix - FW];
                                g2y = yp[pix] - yp[pix - FW]; }
        else                  { g2x = 0.5f * (xp[pix + FW] - xp[pix - FW]);
                                g2y = 0.5f * (yp[pix + FW] - yp[pix - FW]); }

        s += charb(g1x) + charb(g2x) + charb(g1y) + charb(g2y);
    }
    for (int off = 32; off > 0; off >>= 1) s += __shfl_down(s, off, 64);
    __shared__ float shs[4];
    int wave = threadIdx.x >> 6;
    if ((threadIdx.x & 63) == 0) shs[wave] = s;
    __syncthreads();
    if (threadIdx.x == 0)
        part_smooth[sb] = shs[0] + shs[1] + shs[2] + shs[3];
}

// ============ Pass 2: warp + SSIM/pixel partial sums from resized planes ===========
// 1920 blocks; XCD-aware swizzle keeps the 4 parts of one (b,c) on one XCD so each
// src plane (64 KB) is fetched into one L2. ref read = coalesced float2; warp gather
// hits the L2/L3-resident plane. No LDS data path, no barriers, no halo fallback.
__global__ void __launch_bounds__(256, 8) loss(const float* __restrict__ flows,
                                               float* __restrict__ ws)
{
    const float* rs = ws;
    float* part_loss = ws + RS_FLOATS;

    int bid = blockIdx.x;
    int d = (bid & 7) * (LOSS_BLOCKS / 8) + (bid >> 3);   // bijective: 1920 % 8 == 0
    int bc = d >> 2;
    int part = d & 3;
    int b = bc / NC;
    int c = bc % NC;
    int f = c / 3;
    const float2* ref2 = (const float2*)(rs + (size_t)(b * ICH + c) * PL);
    const float*  src  = rs + (size_t)(b * ICH + 3 + c) * PL;
    const float2* fx2  = (const float2*)(flows + (size_t)(b * 2 * NF + 2 * f) * PL);
    const float2* fy2  = (const float2*)(flows + (size_t)(b * 2 * NF + 2 * f + 1) * PL);

    int w0 = (2 * threadIdx.x) & (FW - 1);          // pixels w0, w0+1 (loop-invariant)

    float s_ref = 0.f, s_w = 0.f, s_r2 = 0.f, s_w2 = 0.f, s_rw = 0.f, s_pix = 0.f;
    int base2 = part * 2048;                         // float2 pixel-pair index base
    #pragma unroll 2
    for (int k = 0; k < 8; k++) {
        int p2 = base2 + (int)threadIdx.x + k * 256;
        int h = p2 >> 6;
        float2 rv   = ref2[p2];
        float2 fl_x = fx2[p2];
        float2 fl_y = fy2[p2];
        float ref0 = rv.x, ref1 = rv.y;

        float wv[2];
        #pragma unroll
        for (int q = 0; q < 2; q++) {
            float gx = (float)(w0 + q) + (q ? fl_x.y : fl_x.x);
            float gy = (float)h + (q ? fl_y.y : fl_y.x);
            float x0f = floorf(gx), y0f = floorf(gy);
            float wx = gx - x0f, wy = gy - y0f;
            int x0 = (int)x0f; x0 = min(max(x0, 0), FW - 1);
            int y0 = (int)y0f; y0 = min(max(y0, 0), FH - 1);
            int x1 = min(x0 + 1, FW - 1);
            int y1 = min(y0 + 1, FH - 1);
            const float* r0 = src + (y0 << 7);
            const float* r1 = src + (y1 << 7);
            float v00 = r0[x0], v01 = r0[x1];
            float v10 = r1[x0], v11 = r1[x1];
            float top = v00 * (1.f - wx) + v01 * wx;
            float bot = v10 * (1.f - wx) + v11 * wx;
            wv[q] = top * (1.f - wy) + bot * wy;
        }

        s_ref += ref0 + ref1;
        s_w   += wv[0] + wv[1];
        s_r2  += ref0 * ref0 + ref1 * ref1;
        s_w2  += wv[0] * wv[0] + wv[1] * wv[1];
        s_rw  += ref0 * wv[0] + ref1 * wv[1];
        s_pix += charb(ref0 - wv[0]) + charb(ref1 - wv[1]);
    }
    for (int off = 32; off > 0; off >>= 1) {
        s_ref += __shfl_down(s_ref, off, 64);
        s_w   += __shfl_down(s_w, off, 64);
        s_r2  += __shfl_down(s_r2, off, 64);
        s_w2  += __shfl_down(s_w2, off, 64);
        s_rw  += __shfl_down(s_rw, off, 64);
        s_pix += __shfl_down(s_pix, off, 64);
    }
    __shared__ float sh[4][6];
    int wave = threadIdx.x >> 6;
    if ((threadIdx.x & 63) == 0) {
        sh[wave][0] = s_ref; sh[wave][1] = s_w; sh[wave][2] = s_r2;
        sh[wave][3] = s_w2;  sh[wave][4] = s_rw; sh[wave][5] = s_pix;
    }
    __syncthreads();
    if (threadIdx.x < 6) {
        int j = threadIdx.x;
        part_loss[d * PART_STRIDE + j] = sh[0][j] + sh[1][j] + sh[2][j] + sh[3][j];
    }
}

// ============ finalize: SSIM per (b,c) + combine to scalar ============
__global__ void __launch_bounds__(512) finalize2(const float* __restrict__ ws,
                                                 float* __restrict__ out)
{
    const float* part_loss   = ws + RS_FLOATS;
    const float* part_smooth = ws + RS_FLOATS + LOSS_BLOCKS * PART_STRIDE;
    int tid = threadIdx.x;
    float ssim = 0.f, pix = 0.f, smo = 0.f;
    if (tid < NB * NC) {
        float t0 = 0, t1 = 0, t2 = 0, t3 = 0, t4 = 0;
        for (int q = 0; q < LOSS_SPLIT; q++) {
            const float* a = part_loss + (LOSS_SPLIT * tid + q) * PART_STRIDE;
            t0 += a[0]; t1 += a[1]; t2 += a[2]; t3 += a[3]; t4 += a[4];
            pix += a[5];
        }
        const float N = (float)PL;
        float mu1 = t0 / N, mu2 = t1 / N;
        float var1 = (t2 - t0 * mu1) / (N - 1.f);
        float var2 = (t3 - t1 * mu2) / (N - 1.f);
        float s12 = t4 / N - mu1 * mu2;
        float num = (2.f * mu1 * mu2 + 1e-4f) * (2.f * s12 + 1e-3f);
        float den = (mu1 * mu1 + mu2 * mu2 + 1e-4f) * (var1 + var2 + 1e-3f);
        ssim = num / den;
    }
    if (tid < SMOOTH_BLOCKS) smo = part_smooth[tid];
    __shared__ float sa[512], sb[512], sc[512];
    sa[tid] = ssim; sb[tid] = pix; sc[tid] = smo;
    __syncthreads();
    for (int off = 256; off > 0; off >>= 1) {
        if (tid < off) {
            sa[tid] += sa[tid + off];
            sb[tid] += sb[tid + off];
            sc[tid] += sc[tid + off];
        }
        __syncthreads();
    }
    if (tid == 0) {
        out[0] = sb[0] / (float)(NB * NC * PL)
               + 0.01f * (sc[0] / (float)(NB * NF * PL))
               + sa[0] / (float)(NB * NC);
    }
}

extern "C" void kernel_launch(void* const* d_in, const int* in_sizes, int n_in,
                              void* d_out, int out_size, void* d_ws, size_t ws_size,
                              hipStream_t stream) {
    const float* images = (const float*)d_in[0];
    const float* flows  = (const float*)d_in[1];
    float* ws = (float*)d_ws;   // 34.6 MB resized planes + ~62 KB partials
    resize_smooth<<<RSZ_BLOCKS + SMOOTH_BLOCKS, 256, 0, stream>>>(images, flows, ws);
    loss<<<LOSS_BLOCKS, 256, 0, stream>>>(flows, ws);
    finalize2<<<1, 512, 0, stream>>>(ws, (float*)d_out);
}